// Round 3
// baseline (2766.760 us; speedup 1.0000x reference)
//
#include <hip/hip_runtime.h>
#include <hip/hip_bf16.h>
#include <hip/hip_cooperative_groups.h>
#include <math.h>

namespace cg = cooperative_groups;

#define B_  256
#define T_  40
#define IN_ 2048
#define E_  512
#define H_  1024
#define V_  5000
#define G4_ 4096   // 4*H

typedef __bf16 bf16x8 __attribute__((ext_vector_type(8)));
typedef float  f32x4  __attribute__((ext_vector_type(4)));

__device__ __forceinline__ float sigm(float x) { return 1.0f / (1.0f + expf(-x)); }

__device__ __forceinline__ unsigned short f2b(float x) {
    __hip_bfloat16 h = __float2bfloat16(x);
    return *reinterpret_cast<unsigned short*>(&h);
}

__device__ __forceinline__ unsigned int pack2bf(float lo, float hi) {
    return (unsigned int)f2b(lo) | ((unsigned int)f2b(hi) << 16);
}

#define GLOAD_LDS(g, l) __builtin_amdgcn_global_load_lds(                     \
    (const __attribute__((address_space(1))) unsigned int*)(g),               \
    (__attribute__((address_space(3))) unsigned int*)(l), 16, 0, 0)

// ---------------------------------------------------------------------------
// bf16 MFMA GEMM (unchanged from round 2): C = gather(A) @ B^T + bias + addMat
// ---------------------------------------------------------------------------
__global__ __launch_bounds__(256) void gemm_mfma(
    const unsigned short* __restrict__ A, int lda,
    const int* __restrict__ gidx,
    const unsigned short* __restrict__ Bm, int ldb,
    const float* __restrict__ bias,
    const float* __restrict__ addMat, int rowDiv, long long addStride,
    float* __restrict__ C, int ldc, int N, int K)
{
    __shared__ unsigned short As[128 * 32];
    __shared__ unsigned short Bs[128 * 32];

    const int tid  = threadIdx.x;
    const int wave = tid >> 6, lane = tid & 63;
    const int brow0 = blockIdx.y * 128, bcol0 = blockIdx.x * 128;
    const int wrow0 = (wave >> 1) * 64, wcol0 = (wave & 1) * 64;

    const int srow = lane >> 2;
    const int scol = (lane & 3) * 8;
    const unsigned short* pA[2];
    const unsigned short* pB[2];
    unsigned short* lA[2];
    unsigned short* lB[2];
    #pragma unroll
    for (int i = 0; i < 2; ++i) {
        int seg = wave * 2 + i;
        int row = seg * 16 + srow;
        long long ar = gidx ? (long long)gidx[brow0 + row] : (long long)(brow0 + row);
        pA[i] = A + ar * lda + scol;
        pB[i] = Bm + (long long)(bcol0 + row) * ldb + scol;
        lA[i] = &As[seg * 16 * 32];
        lB[i] = &Bs[seg * 16 * 32];
    }

    f32x4 acc[4][4] = {};
    const int foff = (lane & 15) * 32 + (lane >> 4) * 8;

    for (int k0 = 0; k0 < K; k0 += 32) {
        GLOAD_LDS(pA[0] + k0, lA[0]);
        GLOAD_LDS(pA[1] + k0, lA[1]);
        GLOAD_LDS(pB[0] + k0, lB[0]);
        GLOAD_LDS(pB[1] + k0, lB[1]);
        __syncthreads();

        bf16x8 a[4], b[4];
        #pragma unroll
        for (int m = 0; m < 4; ++m)
            a[m] = *(const bf16x8*)&As[(wrow0 + m * 16) * 32 + foff];
        #pragma unroll
        for (int n = 0; n < 4; ++n)
            b[n] = *(const bf16x8*)&Bs[(wcol0 + n * 16) * 32 + foff];
        #pragma unroll
        for (int m = 0; m < 4; ++m)
            #pragma unroll
            for (int n = 0; n < 4; ++n)
                acc[m][n] = __builtin_amdgcn_mfma_f32_16x16x32_bf16(
                    a[m], b[n], acc[m][n], 0, 0, 0);
        __syncthreads();
    }

    #pragma unroll
    for (int m = 0; m < 4; ++m) {
        #pragma unroll
        for (int j = 0; j < 4; ++j) {
            int row = brow0 + wrow0 + m * 16 + (lane >> 4) * 4 + j;
            const float* addRow = addMat
                ? addMat + (long long)(row / rowDiv) * addStride : nullptr;
            #pragma unroll
            for (int n = 0; n < 4; ++n) {
                int col = bcol0 + wcol0 + n * 16 + (lane & 15);
                if (col < N) {
                    float v = acc[m][n][j];
                    if (bias)   v += bias[col];
                    if (addRow) v += addRow[col];
                    C[(long long)row * ldc + col] = v;
                }
            }
        }
    }
}

// ---------------------------------------------------------------------------
// Persistent cooperative LSTM recurrence.
// Grid: 256 WGs x 256 thr. WG (mb,kb): batch rows mb*64..+64, h-cols kb*16..+16
// (i.e. gate cols {q*1024 + kb*16 + r}, q=0..3).
// W_hh slice [64 gate-rows x 1024 K] bf16 LDS-resident (128 KB, XOR-swizzled).
// Per step: 4 waves x (16 rows x 64 cols) MFMA; cell fully per-lane; c in VGPR.
// ---------------------------------------------------------------------------
__global__ __launch_bounds__(256) void recur_kernel(
    unsigned short* __restrict__ hs,          // [(T+1), B, H] bf16; slot0 = 0
    const float* __restrict__ W_hh,           // [4096, 1024] f32
    const float* __restrict__ gates)          // [B*T, 4096] f32 (row = b*T + t)
{
    extern __shared__ unsigned short lds[];   // 65536 halfwords = 128 KB

    cg::grid_group grid = cg::this_grid();

    const int tid = threadIdx.x;
    const int bid = blockIdx.x;
    const int mb = bid >> 6;          // 0..3
    const int kb = bid & 63;          // 0..63
    const int m0 = mb << 6;

    // ---- stage W_hh slice into LDS (once), bf16 + XOR swizzle ----
    // chunk c: grow = q*16+r (0..63), kc = (c&127)*8
    for (int c = tid; c < 8192; c += 256) {
        int grow = c >> 7;
        int q = grow >> 4, r = grow & 15;
        int kc = (c & 127) << 3;
        int kk = kc >> 5, g = (kc >> 3) & 3;
        const float* src = W_hh + (size_t)((q << 10) + (kb << 4) + r) * H_ + kc;
        float4 f0 = *(const float4*)src;
        float4 f1 = *(const float4*)(src + 4);
        uint4 pk;
        pk.x = pack2bf(f0.x, f0.y);
        pk.y = pack2bf(f0.z, f0.w);
        pk.z = pack2bf(f1.x, f1.y);
        pk.w = pack2bf(f1.z, f1.w);
        int byteoff = (((q << 5) + kk) << 10) + (r << 6) + (g << 4);
        byteoff ^= (r & 7) << 4;
        *(uint4*)((char*)lds + byteoff) = pk;
    }
    __syncthreads();

    const int lane = tid & 63, w = tid >> 6;
    const int r16 = lane & 15, g4 = lane >> 4;
    const int boff = ((r16 << 6) + (g4 << 4)) ^ ((r16 & 7) << 4);

    // A-fragment source row (per lane): m0 + w*16 + r16
    const size_t a_row_off = ((size_t)(m0 + (w << 4) + r16) << 10) + (g4 << 3);
    // output/cell rows (per lane): m0 + w*16 + g4*4 + j
    const int orow0 = m0 + (w << 4) + (g4 << 2);

    float cc[4] = {0.f, 0.f, 0.f, 0.f};

    for (int t = 0; t < T_; ++t) {
        // gates_x loads for this step (issued early, consumed after MFMA)
        float gv[4][4];
        const float* gbase = gates + ((size_t)orow0 * T_ + t) * G4_ + (kb << 4) + r16;
        #pragma unroll
        for (int j = 0; j < 4; ++j)
            #pragma unroll
            for (int q = 0; q < 4; ++q)
                gv[q][j] = gbase[(size_t)j * T_ * G4_ + (q << 10)];

        const unsigned short* hp = hs + (size_t)t * (B_ * H_) + a_row_off;

        f32x4 acc[4] = {};
        #pragma unroll
        for (int kq = 0; kq < 4; ++kq) {
            bf16x8 a8[8];
            #pragma unroll
            for (int u = 0; u < 8; ++u)
                a8[u] = *(const bf16x8*)(hp + ((kq << 3) + u) * 32);
            #pragma unroll
            for (int u = 0; u < 8; ++u) {
                int kk = (kq << 3) + u;
                #pragma unroll
                for (int q = 0; q < 4; ++q) {
                    bf16x8 bv = *(const bf16x8*)((const char*)lds +
                                 ((((q << 5) + kk) << 10) + boff));
                    acc[q] = __builtin_amdgcn_mfma_f32_16x16x32_bf16(
                        a8[u], bv, acc[q], 0, 0, 0);
                }
            }
        }

        // cell (per-lane: rows orow0+j, h-col kb*16+r16)
        unsigned short* hw = hs + (size_t)(t + 1) * (B_ * H_) +
                             ((size_t)orow0 << 10) + (kb << 4) + r16;
        #pragma unroll
        for (int j = 0; j < 4; ++j) {
            float gi = acc[0][j] + gv[0][j];
            float gf = acc[1][j] + gv[1][j];
            float gg = acc[2][j] + gv[2][j];
            float go = acc[3][j] + gv[3][j];
            float c2 = sigm(gf) * cc[j] + sigm(gi) * tanhf(gg);
            cc[j] = c2;
            hw[(size_t)j << 10] = f2b(sigm(go) * tanhf(c2));
        }

        if (t != T_ - 1) {
            __threadfence();
            grid.sync();
        }
    }
}

// ---------------------------------------------------------------------------
// fp32 tiled GEMM (two small GEMMs): C = A @ B^T + bias
// ---------------------------------------------------------------------------
__global__ __launch_bounds__(256) void gemm_bt(
    const float* __restrict__ A, int lda,
    const float* __restrict__ Bm, int ldb,
    const float* __restrict__ bias,
    float* __restrict__ C, int ldc, int N, int K)
{
    const int BK = 16;
    __shared__ float As[BK][64];
    __shared__ float Bs[BK][64];

    const int tx = threadIdx.x, ty = threadIdx.y;
    const int tid = ty * 16 + tx;
    const int brow0 = blockIdx.y * 64;
    const int bcol0 = blockIdx.x * 64;

    const int e0   = tid * 4;
    const int la_r = e0 / BK;
    const int la_k = e0 % BK;

    const long long arow_base = (long long)(brow0 + la_r) * lda;
    const int bRowG = bcol0 + la_r;
    const bool bValid = (bRowG < N);
    const long long brow_base = (long long)bRowG * ldb;

    float acc[4][4] = {};

    for (int k0 = 0; k0 < K; k0 += BK) {
        float4 av = *(const float4*)(A + arow_base + k0 + la_k);
        float4 bv = make_float4(0.f, 0.f, 0.f, 0.f);
        if (bValid) bv = *(const float4*)(Bm + brow_base + k0 + la_k);

        As[la_k + 0][la_r] = av.x; As[la_k + 1][la_r] = av.y;
        As[la_k + 2][la_r] = av.z; As[la_k + 3][la_r] = av.w;
        Bs[la_k + 0][la_r] = bv.x; Bs[la_k + 1][la_r] = bv.y;
        Bs[la_k + 2][la_r] = bv.z; Bs[la_k + 3][la_r] = bv.w;
        __syncthreads();

        #pragma unroll
        for (int kk = 0; kk < BK; ++kk) {
            float af[4], bf[4];
            #pragma unroll
            for (int i = 0; i < 4; ++i) af[i] = As[kk][ty * 4 + i];
            #pragma unroll
            for (int j = 0; j < 4; ++j) bf[j] = Bs[kk][tx * 4 + j];
            #pragma unroll
            for (int i = 0; i < 4; ++i)
                #pragma unroll
                for (int j = 0; j < 4; ++j)
                    acc[i][j] = fmaf(af[i], bf[j], acc[i][j]);
        }
        __syncthreads();
    }

    #pragma unroll
    for (int i = 0; i < 4; ++i) {
        const int row = brow0 + ty * 4 + i;
        #pragma unroll
        for (int j = 0; j < 4; ++j) {
            const int col = bcol0 + tx * 4 + j;
            if (col < N) {
                float v = acc[i][j];
                if (bias) v += bias[col];
                C[(long long)row * ldc + col] = v;
            }
        }
    }
}

// ---------------------------------------------------------------------------
// f32 -> bf16 conversion with optional column slice + zero row padding
// ---------------------------------------------------------------------------
__global__ void conv2bf(const float* __restrict__ src, unsigned short* __restrict__ dst,
                        int rows, int rowsPad, int cols, int srcld, int srccol0)
{
    int i = blockIdx.x * blockDim.x + threadIdx.x;
    int c4n = cols >> 2;
    if (i >= rowsPad * c4n) return;
    int r = i / c4n, c4 = i % c4n;
    ushort4 o;
    if (r < rows) {
        float4 v = *(const float4*)(src + (long long)r * srcld + srccol0 + c4 * 4);
        o.x = f2b(v.x); o.y = f2b(v.y); o.z = f2b(v.z); o.w = f2b(v.w);
    } else {
        o = make_ushort4(0, 0, 0, 0);
    }
    *(ushort4*)(dst + (long long)r * cols + c4 * 4) = o;
}

// ---------------------------------------------------------------------------
// prep: gather indices + combined bias
// ---------------------------------------------------------------------------
__global__ void prep_kernel(const int* __restrict__ labels,
                            const float* __restrict__ b_ih,
                            const float* __restrict__ b_hh,
                            int* __restrict__ idxEmb,
                            int* __restrict__ idxLog,
                            float* __restrict__ bsum)
{
    int r = blockIdx.x * blockDim.x + threadIdx.x;
    if (r < B_ * T_) {
        int b = r / T_, t = r % T_;
        int tsrc = (t == 0) ? (T_ - 1) : (t - 1);
        idxEmb[r] = labels[b * T_ + tsrc];
        idxLog[r] = (t + 1) * B_ + b;   // hs slot t+1 holds h_t
    }
    if (r < G4_) bsum[r] = b_ih[r] + b_hh[r];
}

extern "C" void kernel_launch(void* const* d_in, const int* in_sizes, int n_in,
                              void* d_out, int out_size, void* d_ws, size_t ws_size,
                              hipStream_t stream)
{
    const float* X      = (const float*)d_in[0];
    const int*   labels = (const int*)  d_in[1];
    const float* W_f    = (const float*)d_in[2];
    const float* b_f    = (const float*)d_in[3];
    const float* emb    = (const float*)d_in[4];
    const float* W_ih   = (const float*)d_in[5];
    const float* W_hh   = (const float*)d_in[6];
    const float* b_ih   = (const float*)d_in[7];
    const float* b_hh   = (const float*)d_in[8];
    const float* W_out  = (const float*)d_in[9];
    const float* b_out  = (const float*)d_in[10];
    float* out = (float*)d_out;
    (void)in_sizes; (void)n_in; (void)out_size; (void)ws_size;

    char* ws = (char*)d_ws;
    size_t off = 0;
    auto alloc = [&](size_t bytes) {
        void* p = ws + off;
        off += (bytes + 255) & ~(size_t)255;
        return p;
    };
    unsigned short* emb_bf  = (unsigned short*)alloc((size_t)(V_ + 1) * E_ * 2);
    unsigned short* WihE_bf = (unsigned short*)alloc((size_t)G4_ * E_ * 2);
    unsigned short* Wout_bf = (unsigned short*)alloc((size_t)5120 * H_ * 2);
    unsigned short* hs_bf   = (unsigned short*)alloc((size_t)(T_ + 1) * B_ * H_ * 2);
    float* features = (float*)alloc(B_ * E_ * 4);
    float* bsum     = (float*)alloc(G4_ * 4);
    int*   idxEmb   = (int*)  alloc(B_ * T_ * 4);
    int*   idxLog   = (int*)  alloc(B_ * T_ * 4);

    // d_out reuse: gates [B*T,4H] at the front (fully consumed by the
    // recurrence before the logits GEMM overwrites d_out); baseMat in tail.
    float* gates   = out;
    float* baseMat = out + (size_t)B_ * T_ * G4_;   // 41.94M + 1.05M < 51.2M

    hipMemsetAsync(hs_bf, 0, B_ * H_ * 2, stream);  // h0 = 0 (slot 0)

    prep_kernel<<<(B_ * T_ + 255) / 256, 256, 0, stream>>>(
        labels, b_ih, b_hh, idxEmb, idxLog, bsum);

    {
        int n;
        n = (V_ + 1) * E_ / 4;
        conv2bf<<<(n + 255) / 256, 256, 0, stream>>>(emb, emb_bf, V_ + 1, V_ + 1, E_, E_, 0);
        n = G4_ * E_ / 4;
        conv2bf<<<(n + 255) / 256, 256, 0, stream>>>(W_ih, WihE_bf, G4_, G4_, E_, 2 * E_, E_);
        n = 5120 * H_ / 4;
        conv2bf<<<(n + 255) / 256, 256, 0, stream>>>(W_out, Wout_bf, V_, 5120, H_, H_, 0);
    }

    dim3 thr(16, 16);

    // features = X @ W_f^T + b_f            [256,512] K=2048 (fp32)
    gemm_bt<<<dim3(E_ / 64, B_ / 64), thr, 0, stream>>>(
        X, IN_, W_f, IN_, b_f, features, E_, E_, IN_);

    // base = features @ W_ih[:, :E]^T + (b_ih + b_hh)   [256,4096] K=512 (fp32)
    gemm_bt<<<dim3(G4_ / 64, B_ / 64), thr, 0, stream>>>(
        features, E_, W_ih, 2 * E_, bsum, baseMat, G4_, G4_, E_);

    // gates = gather(emb_bf) @ WihE^T + base[row/T]   [10240,4096] K=512 (MFMA)
    gemm_mfma<<<dim3(G4_ / 128, (B_ * T_) / 128), 256, 0, stream>>>(
        emb_bf, E_, idxEmb, WihE_bf, E_, nullptr,
        baseMat, T_, G4_, gates, G4_, G4_, E_);

    // ---- persistent cooperative recurrence (all 40 steps) ----
    {
        static int attr_done = 0;
        // idempotent, not a stream op — safe under graph capture
        hipFuncSetAttribute((const void*)recur_kernel,
                            hipFuncAttributeMaxDynamicSharedMemorySize, 131072);
        (void)attr_done;
        void* kargs[] = { (void*)&hs_bf, (void*)&W_hh, (void*)&gates };
        hipLaunchCooperativeKernel((const void*)recur_kernel,
                                   dim3(256), dim3(256), kargs, 131072, stream);
    }

    // logits = gather(hs_bf) @ W_out^T + b_out   [10240,5000] K=1024 (MFMA)
    gemm_mfma<<<dim3(5120 / 128, (B_ * T_) / 128), 256, 0, stream>>>(
        hs_bf, H_, idxLog, Wout_bf, H_, b_out,
        nullptr, 1, 0, out, V_, V_, H_);
}